// Round 7
// baseline (118.642 us; speedup 1.0000x reference)
//
#include <hip/hip_runtime.h>
#include <math.h>

#define COND_C 6
#define NOUT 11   // N_MODES*DIM*2 + N_MODES + 1

typedef float f32x2 __attribute__((ext_vector_type(2)));

static constexpr float LOG2E         = 1.44269504088896340736f;
static constexpr float LN2           = 0.69314718055994530942f;
static constexpr float INV_2PI       = 0.15915494309189533577f;
static constexpr float NEG_HALF_L2E  = -0.72134752044448170368f;  // -0.5*log2(e)
static constexpr float INV_PI        = 0.31830988618f;

// packed-weight layout in d_ws (floats):
//   [0..255]    W1T: row j (32 rows) = {W1[0][j]..W1[5][j], b1[j], 0}   (8 floats)
//   [256..639]  W2p: row j (32 rows) = {W2[j][0]..W2[j][10], 0}          (12 floats)
//   [640..651]  b2p: {b2[0]..b2[10], 0}
#define WS_W2_OFF 256
#define WS_B2_OFF 640
#define WS_FLOATS 656

__device__ __forceinline__ float rcp_f(float x)  { return __builtin_amdgcn_rcpf(x); }
__device__ __forceinline__ float exp2_f(float x) { return __builtin_amdgcn_exp2f(x); }
__device__ __forceinline__ float log2_f(float x) { return __builtin_amdgcn_logf(x); }
__device__ __forceinline__ float sqrt_f(float x) { return __builtin_amdgcn_sqrtf(x); }
// v_sin_f32 / v_cos_f32 take input in REVOLUTIONS: sin_rev(x) = sin(2*pi*x)
__device__ __forceinline__ float sin_rev(float x) { return __builtin_amdgcn_sinf(x); }
__device__ __forceinline__ float cos_rev(float x) { return __builtin_amdgcn_cosf(x); }

__device__ __forceinline__ f32x2 fma2(f32x2 a, f32x2 b, f32x2 c) {
    return __builtin_elementwise_fma(a, b, c);
}
__device__ __forceinline__ f32x2 bc2(float w) { return (f32x2){w, w}; }

struct RowOut { float z0, z1, lp; };

// Per-row epilogue: sampling + log-density (product form, merged trig).
__device__ __forceinline__ RowOut epilogue(const float* o, float rdn, float u1)
{
    float loc00 = o[0], loc01 = o[1], loc10 = o[2], loc11 = o[3];
    float ls00  = o[4], ls01  = o[5], ls10  = o[6], ls11  = o[7];
    float aw0 = fabsf(o[8]), aw1 = fabsf(o[9]), aw2 = fabsf(o[10]);
    float rinv = rcp_f(aw0 + aw1 + aw2);
    float w0 = aw0 * rinv, w1 = aw1 * rinv, w2 = aw2 * rinv;

    float wc0 = w0;
    float wc1 = w0 + w1;
    bool g1 = rdn < wc0;
    bool g2 = (!g1) && (rdn < wc1);
    bool gauss = g1 || g2;

    float num = rdn - (g1 ? 0.0f : (g2 ? wc0 : wc1));
    float den = g1 ? wc0 : (g2 ? w1 : w2);
    float u0  = num * rcp_f(den);

    // Box-Muller radius (gauss only; harmless otherwise)
    float U1 = gauss ? u0 : 0.5f;
    float R = sqrt_f(-1.38629436111989062f * log2_f(U1));  // sqrt(-2 ln U1)

    // Lambert geometry
    float wo0 = fmaf(2.0f, u0, -1.0f);
    float wo1 = fmaf(2.0f, u1, -1.0f);
    bool c1b = (fabsf(wo0) > fabsf(wo1)) && !((wo0 == 0.0f) && (wo1 == 0.0f));
    float sden = c1b ? wo0 : ((wo1 == 0.0f) ? 1.0f : wo1);
    float rnum = c1b ? wo1 : wo0;
    float r = rnum * rcp_f(sden);
    float a_rev = c1b ? (0.125f * r) : fmaf(-0.125f, r, 0.25f);
    float amp = c1b ? wo0 : wo1;   // both-zero -> amp = 0 -> z = 0

    // merged trig: gauss angle = u1 rev; lambert angle = a_rev
    float angle = gauss ? u1 : a_rev;
    float ca = cos_rev(angle);
    float sa = sin_rev(angle);

    // inverse scales (needed for density anyway)
    float ie00 = exp2_f(-ls00 * LOG2E), ie01 = exp2_f(-ls01 * LOG2E);
    float ie10 = exp2_f(-ls10 * LOG2E), ie11 = exp2_f(-ls11 * LOG2E);

    // z = A*{cos,sin}(angle) + B
    float scale0 = rcp_f(g2 ? ie10 : ie00);   // exp(ls_sel0)
    float scale1 = rcp_f(g2 ? ie11 : ie01);
    float A0 = gauss ? (R * scale0) : amp;
    float A1 = gauss ? (R * scale1) : amp;
    float B0 = gauss ? (g2 ? loc10 : loc00) : 0.0f;
    float B1 = gauss ? (g2 ? loc11 : loc01) : 0.0f;
    float z0 = fmaf(A0, ca, B0);
    float z1 = fmaf(A1, sa, B1);

    // log density, product form
    float e00 = (z0 - loc00) * ie00;
    float e01 = (z1 - loc01) * ie01;
    float e10 = (z0 - loc10) * ie10;
    float e11 = (z1 - loc11) * ie11;
    float q0 = fmaf(e00, e00, e01 * e01);
    float q1 = fmaf(e10, e10, e11 * e11);
    float p0 = (w0 + 1e-5f) * INV_2PI * (ie00 * ie01) * exp2_f(NEG_HALF_L2E * q0);
    float p1 = (w1 + 1e-5f) * INV_2PI * (ie10 * ie11) * exp2_f(NEG_HALF_L2E * q1);
    bool invalid = fmaf(z0, z0, z1 * z1) > 1.0f;
    float pl = invalid ? 1e-5f : (INV_PI + 1e-5f);
    float p2 = pl * w2;

    RowOut out;
    out.z0 = z0; out.z1 = z1;
    out.lp = log2_f(p0 + p1 + p2) * LN2;
    return out;
}

// ---- setup: repack weights into d_ws for float4 immediate-offset access ----
__global__ void pack_weights_kernel(const float* __restrict__ W1,
                                    const float* __restrict__ b1,
                                    const float* __restrict__ W2,
                                    const float* __restrict__ b2,
                                    float* __restrict__ ws)
{
    int t = threadIdx.x;   // one block of 672
    if (t < 256) {         // W1T + b1: ws[j*8 + c]
        int j = t >> 3, c = t & 7;
        ws[t] = (c < 6) ? W1[c * 32 + j] : ((c == 6) ? b1[j] : 0.0f);
    } else if (t < 640) {  // W2 padded rows: ws[256 + j*12 + k]
        int u = t - 256;
        int j = u / 12, k = u - j * 12;
        ws[t] = (k < 11) ? W2[j * 11 + k] : 0.0f;
    } else if (t < WS_FLOATS) {
        int k = t - WS_B2_OFF;
        ws[t] = (k < 11) ? b2[k] : 0.0f;
    }
}

__global__ __launch_bounds__(256)
void gmm_weighted_cond_kernel(const float* __restrict__ cond,
                              const float* __restrict__ seed,
                              const float* __restrict__ ws,
                              float* __restrict__ z_out,
                              float* __restrict__ logp_out,
                              int Nquads)
{
    int t = blockIdx.x * blockDim.x + threadIdx.x;
    if (t >= Nquads) return;

    const float4* W1T = reinterpret_cast<const float4*>(ws);                 // 2 float4 per j
    const float4* W2p = reinterpret_cast<const float4*>(ws + WS_W2_OFF);     // 3 float4 per j
    const float4* b2p = reinterpret_cast<const float4*>(ws + WS_B2_OFF);     // 3 float4

    // ---- load 4 rows of cond (24 floats = 6x float4) ----
    const float4* cp = reinterpret_cast<const float4*>(cond) + (size_t)t * 6;
    float4 c0 = cp[0], c1 = cp[1], c2 = cp[2], c3 = cp[3], c4 = cp[4], c5 = cp[5];
    // pair A = rows 0,1 ; pair B = rows 2,3
    f32x2 xA0 = {c0.x, c1.z}, xA1 = {c0.y, c1.w}, xA2 = {c0.z, c2.x};
    f32x2 xA3 = {c0.w, c2.y}, xA4 = {c1.x, c2.z}, xA5 = {c1.y, c2.w};
    f32x2 xB0 = {c3.x, c4.z}, xB1 = {c3.y, c4.w}, xB2 = {c3.z, c5.x};
    f32x2 xB3 = {c3.w, c5.y}, xB4 = {c4.x, c5.z}, xB5 = {c4.y, c5.w};

    // ---- MLP: per j, 5 float4 weight loads feed 34 pk-FMAs (4 rows) ----
    float4 bq0 = b2p[0], bq1 = b2p[1], bq2 = b2p[2];
    f32x2 oA[NOUT] = {
        bc2(bq0.x), bc2(bq0.y), bc2(bq0.z), bc2(bq0.w),
        bc2(bq1.x), bc2(bq1.y), bc2(bq1.z), bc2(bq1.w),
        bc2(bq2.x), bc2(bq2.y), bc2(bq2.z)
    };
    f32x2 oB[NOUT];
#pragma unroll
    for (int k = 0; k < NOUT; ++k) oB[k] = oA[k];

#pragma unroll
    for (int j = 0; j < 32; ++j) {
        float4 wa = W1T[j * 2];        // W1[0..3][j]
        float4 wb = W1T[j * 2 + 1];    // W1[4][j], W1[5][j], b1[j], 0
        f32x2 accA = bc2(wb.z);
        f32x2 accB = accA;
        accA = fma2(xA0, bc2(wa.x), accA);  accB = fma2(xB0, bc2(wa.x), accB);
        accA = fma2(xA1, bc2(wa.y), accA);  accB = fma2(xB1, bc2(wa.y), accB);
        accA = fma2(xA2, bc2(wa.z), accA);  accB = fma2(xB2, bc2(wa.z), accB);
        accA = fma2(xA3, bc2(wa.w), accA);  accB = fma2(xB3, bc2(wa.w), accB);
        accA = fma2(xA4, bc2(wb.x), accA);  accB = fma2(xB4, bc2(wb.x), accB);
        accA = fma2(xA5, bc2(wb.y), accA);  accB = fma2(xB5, bc2(wb.y), accB);
        accA = __builtin_elementwise_max(accA, (f32x2){0.0f, 0.0f});
        accB = __builtin_elementwise_max(accB, (f32x2){0.0f, 0.0f});

        float4 q0 = W2p[j * 3];
        float4 q1 = W2p[j * 3 + 1];
        float4 q2 = W2p[j * 3 + 2];
        oA[0]  = fma2(accA, bc2(q0.x), oA[0]);   oB[0]  = fma2(accB, bc2(q0.x), oB[0]);
        oA[1]  = fma2(accA, bc2(q0.y), oA[1]);   oB[1]  = fma2(accB, bc2(q0.y), oB[1]);
        oA[2]  = fma2(accA, bc2(q0.z), oA[2]);   oB[2]  = fma2(accB, bc2(q0.z), oB[2]);
        oA[3]  = fma2(accA, bc2(q0.w), oA[3]);   oB[3]  = fma2(accB, bc2(q0.w), oB[3]);
        oA[4]  = fma2(accA, bc2(q1.x), oA[4]);   oB[4]  = fma2(accB, bc2(q1.x), oB[4]);
        oA[5]  = fma2(accA, bc2(q1.y), oA[5]);   oB[5]  = fma2(accB, bc2(q1.y), oB[5]);
        oA[6]  = fma2(accA, bc2(q1.z), oA[6]);   oB[6]  = fma2(accB, bc2(q1.z), oB[6]);
        oA[7]  = fma2(accA, bc2(q1.w), oA[7]);   oB[7]  = fma2(accB, bc2(q1.w), oB[7]);
        oA[8]  = fma2(accA, bc2(q2.x), oA[8]);   oB[8]  = fma2(accB, bc2(q2.x), oB[8]);
        oA[9]  = fma2(accA, bc2(q2.y), oA[9]);   oB[9]  = fma2(accB, bc2(q2.y), oB[9]);
        oA[10] = fma2(accA, bc2(q2.z), oA[10]);  oB[10] = fma2(accB, bc2(q2.z), oB[10]);
    }

    // ---- seeds for 4 rows (2x float4) ----
    const float4* sp = reinterpret_cast<const float4*>(seed) + (size_t)t * 2;
    float4 sd0 = sp[0], sd1 = sp[1];

    float o0[NOUT], o1[NOUT], o2[NOUT], o3[NOUT];
#pragma unroll
    for (int k = 0; k < NOUT; ++k) {
        o0[k] = oA[k].x; o1[k] = oA[k].y;
        o2[k] = oB[k].x; o3[k] = oB[k].y;
    }

    RowOut r0 = epilogue(o0, sd0.x, sd0.y);
    RowOut r1 = epilogue(o1, sd0.z, sd0.w);
    RowOut r2 = epilogue(o2, sd1.x, sd1.y);
    RowOut r3 = epilogue(o3, sd1.z, sd1.w);

    // ---- stores: z (N,2) = 2x float4, log_p = 1x float4 ----
    float4* zp = reinterpret_cast<float4*>(z_out) + (size_t)t * 2;
    zp[0] = make_float4(r0.z0, r0.z1, r1.z0, r1.z1);
    zp[1] = make_float4(r2.z0, r2.z1, r3.z0, r3.z1);
    reinterpret_cast<float4*>(logp_out)[t] = make_float4(r0.lp, r1.lp, r2.lp, r3.lp);
}

extern "C" void kernel_launch(void* const* d_in, const int* in_sizes, int n_in,
                              void* d_out, int out_size, void* d_ws, size_t ws_size,
                              hipStream_t stream)
{
    const float* cond = (const float*)d_in[0];
    const float* seed = (const float*)d_in[1];
    const float* W1   = (const float*)d_in[2];
    const float* b1   = (const float*)d_in[3];
    const float* W2   = (const float*)d_in[4];
    const float* b2   = (const float*)d_in[5];

    int N = in_sizes[1] / 2;   // randseed is (N,2)
    int Nquads = N / 4;

    float* ws = (float*)d_ws;
    float* z_out    = (float*)d_out;                   // first 2N floats
    float* logp_out = (float*)d_out + 2 * (size_t)N;   // next N floats

    pack_weights_kernel<<<1, 672, 0, stream>>>(W1, b1, W2, b2, ws);

    int block = 256;
    int grid = (Nquads + block - 1) / block;
    gmm_weighted_cond_kernel<<<grid, block, 0, stream>>>(
        cond, seed, ws, z_out, logp_out, Nquads);
}

// Round 8
// 42.196 us; speedup vs baseline: 2.8117x; 2.8117x over previous
//
#include <hip/hip_runtime.h>
#include <math.h>

#define COND_C 6
#define NOUT 11   // N_MODES*DIM*2 + N_MODES + 1

typedef float f32x2 __attribute__((ext_vector_type(2)));

static constexpr float LOG2E         = 1.44269504088896340736f;
static constexpr float LN2           = 0.69314718055994530942f;
static constexpr float INV_2PI       = 0.15915494309189533577f;
static constexpr float NEG_HALF_L2E  = -0.72134752044448170368f;  // -0.5*log2(e)
static constexpr float INV_PI        = 0.31830988618f;

// packed-weight layout in d_ws (floats):
//   [0..255]    W1T: row j (32 rows) = {W1[0][j]..W1[5][j], b1[j], 0}   (8 floats)
//   [256..639]  W2p: row j (32 rows) = {W2[j][0]..W2[j][10], 0}          (12 floats)
//   [640..651]  b2p: {b2[0]..b2[10], 0}
#define WS_W2_OFF 256
#define WS_B2_OFF 640
#define WS_FLOATS 656

__device__ __forceinline__ float rcp_f(float x)  { return __builtin_amdgcn_rcpf(x); }
__device__ __forceinline__ float exp2_f(float x) { return __builtin_amdgcn_exp2f(x); }
__device__ __forceinline__ float log2_f(float x) { return __builtin_amdgcn_logf(x); }
__device__ __forceinline__ float sqrt_f(float x) { return __builtin_amdgcn_sqrtf(x); }
// v_sin_f32 / v_cos_f32 take input in REVOLUTIONS: sin_rev(x) = sin(2*pi*x)
__device__ __forceinline__ float sin_rev(float x) { return __builtin_amdgcn_sinf(x); }
__device__ __forceinline__ float cos_rev(float x) { return __builtin_amdgcn_cosf(x); }

__device__ __forceinline__ f32x2 fma2(f32x2 a, f32x2 b, f32x2 c) {
    return __builtin_elementwise_fma(a, b, c);
}
__device__ __forceinline__ f32x2 bc2(float w) { return (f32x2){w, w}; }

struct RowOut { float z0, z1, lp; };

// Per-row epilogue: sampling + log-density (product form, merged trig).
__device__ __forceinline__ RowOut epilogue(const float* o, float rdn, float u1)
{
    float loc00 = o[0], loc01 = o[1], loc10 = o[2], loc11 = o[3];
    float ls00  = o[4], ls01  = o[5], ls10  = o[6], ls11  = o[7];
    float aw0 = fabsf(o[8]), aw1 = fabsf(o[9]), aw2 = fabsf(o[10]);
    float rinv = rcp_f(aw0 + aw1 + aw2);
    float w0 = aw0 * rinv, w1 = aw1 * rinv, w2 = aw2 * rinv;

    float wc0 = w0;
    float wc1 = w0 + w1;
    bool g1 = rdn < wc0;
    bool g2 = (!g1) && (rdn < wc1);
    bool gauss = g1 || g2;

    float num = rdn - (g1 ? 0.0f : (g2 ? wc0 : wc1));
    float den = g1 ? wc0 : (g2 ? w1 : w2);
    float u0  = num * rcp_f(den);

    // Box-Muller radius (gauss only; harmless otherwise)
    float U1 = gauss ? u0 : 0.5f;
    float R = sqrt_f(-1.38629436111989062f * log2_f(U1));  // sqrt(-2 ln U1)

    // Lambert geometry
    float wo0 = fmaf(2.0f, u0, -1.0f);
    float wo1 = fmaf(2.0f, u1, -1.0f);
    bool c1b = (fabsf(wo0) > fabsf(wo1)) && !((wo0 == 0.0f) && (wo1 == 0.0f));
    float sden = c1b ? wo0 : ((wo1 == 0.0f) ? 1.0f : wo1);
    float rnum = c1b ? wo1 : wo0;
    float r = rnum * rcp_f(sden);
    float a_rev = c1b ? (0.125f * r) : fmaf(-0.125f, r, 0.25f);
    float amp = c1b ? wo0 : wo1;   // both-zero -> amp = 0 -> z = 0

    // merged trig: gauss angle = u1 rev; lambert angle = a_rev
    float angle = gauss ? u1 : a_rev;
    float ca = cos_rev(angle);
    float sa = sin_rev(angle);

    // inverse scales (needed for density anyway)
    float ie00 = exp2_f(-ls00 * LOG2E), ie01 = exp2_f(-ls01 * LOG2E);
    float ie10 = exp2_f(-ls10 * LOG2E), ie11 = exp2_f(-ls11 * LOG2E);

    // z = A*{cos,sin}(angle) + B
    float scale0 = rcp_f(g2 ? ie10 : ie00);   // exp(ls_sel0)
    float scale1 = rcp_f(g2 ? ie11 : ie01);
    float A0 = gauss ? (R * scale0) : amp;
    float A1 = gauss ? (R * scale1) : amp;
    float B0 = gauss ? (g2 ? loc10 : loc00) : 0.0f;
    float B1 = gauss ? (g2 ? loc11 : loc01) : 0.0f;
    float z0 = fmaf(A0, ca, B0);
    float z1 = fmaf(A1, sa, B1);

    // log density, product form
    float e00 = (z0 - loc00) * ie00;
    float e01 = (z1 - loc01) * ie01;
    float e10 = (z0 - loc10) * ie10;
    float e11 = (z1 - loc11) * ie11;
    float q0 = fmaf(e00, e00, e01 * e01);
    float q1 = fmaf(e10, e10, e11 * e11);
    float p0 = (w0 + 1e-5f) * INV_2PI * (ie00 * ie01) * exp2_f(NEG_HALF_L2E * q0);
    float p1 = (w1 + 1e-5f) * INV_2PI * (ie10 * ie11) * exp2_f(NEG_HALF_L2E * q1);
    bool invalid = fmaf(z0, z0, z1 * z1) > 1.0f;
    float pl = invalid ? 1e-5f : (INV_PI + 1e-5f);
    float p2 = pl * w2;

    RowOut out;
    out.z0 = z0; out.z1 = z1;
    out.lp = log2_f(p0 + p1 + p2) * LN2;
    return out;
}

// ---- setup: repack weights into d_ws for float4 immediate-offset access ----
__global__ void pack_weights_kernel(const float* __restrict__ W1,
                                    const float* __restrict__ b1,
                                    const float* __restrict__ W2,
                                    const float* __restrict__ b2,
                                    float* __restrict__ ws)
{
    int t = threadIdx.x;   // one block of 672
    if (t < 256) {         // W1T + b1: ws[j*8 + c]
        int j = t >> 3, c = t & 7;
        ws[t] = (c < 6) ? W1[c * 32 + j] : ((c == 6) ? b1[j] : 0.0f);
    } else if (t < 640) {  // W2 padded rows: ws[256 + j*12 + k]
        int u = t - 256;
        int j = u / 12, k = u - j * 12;
        ws[t] = (k < 11) ? W2[j * 11 + k] : 0.0f;
    } else if (t < WS_FLOATS) {
        int k = t - WS_B2_OFF;
        ws[t] = (k < 11) ? b2[k] : 0.0f;
    }
}

__global__ __launch_bounds__(256)
void gmm_weighted_cond_kernel(const float* __restrict__ cond,
                              const float* __restrict__ seed,
                              const float* __restrict__ ws,
                              float* __restrict__ z_out,
                              float* __restrict__ logp_out,
                              int Npairs)
{
    int t = blockIdx.x * blockDim.x + threadIdx.x;
    if (t >= Npairs) return;

    const float4* W1T = reinterpret_cast<const float4*>(ws);                 // 2 float4 per j
    const float4* W2p = reinterpret_cast<const float4*>(ws + WS_W2_OFF);     // 3 float4 per j
    const float4* b2p = reinterpret_cast<const float4*>(ws + WS_B2_OFF);     // 3 float4

    // ---- load 2 rows of cond (12 floats = 3x float4) ----
    const float4* cp = reinterpret_cast<const float4*>(cond) + (size_t)t * 3;
    float4 ca = cp[0], cb = cp[1], cc = cp[2];
    // row A: ca.x ca.y ca.z ca.w cb.x cb.y ; row B: cb.z cb.w cc.x cc.y cc.z cc.w
    f32x2 x0 = {ca.x, cb.z}, x1 = {ca.y, cb.w}, x2 = {ca.z, cc.x};
    f32x2 x3 = {ca.w, cc.y}, x4 = {cb.x, cc.z}, x5 = {cb.y, cc.w};

    // ---- MLP: ROLLED j-loop (32 iters). Body ~40 insts: 5 uniform float4
    // weight reads + 17 pk-FMA. Small I$ footprint; per-iteration weight
    // fetch stalls interleave across resident waves instead of chaining
    // through a 10KB straight-line body. ----
    float4 bq0 = b2p[0], bq1 = b2p[1], bq2 = b2p[2];
    f32x2 o[NOUT] = {
        bc2(bq0.x), bc2(bq0.y), bc2(bq0.z), bc2(bq0.w),
        bc2(bq1.x), bc2(bq1.y), bc2(bq1.z), bc2(bq1.w),
        bc2(bq2.x), bc2(bq2.y), bc2(bq2.z)
    };
#pragma unroll 1
    for (int j = 0; j < 32; ++j) {
        float4 wa = W1T[j * 2];        // W1[0..3][j]
        float4 wb = W1T[j * 2 + 1];    // W1[4][j], W1[5][j], b1[j], 0
        f32x2 acc = bc2(wb.z);
        acc = fma2(x0, bc2(wa.x), acc);
        acc = fma2(x1, bc2(wa.y), acc);
        acc = fma2(x2, bc2(wa.z), acc);
        acc = fma2(x3, bc2(wa.w), acc);
        acc = fma2(x4, bc2(wb.x), acc);
        acc = fma2(x5, bc2(wb.y), acc);
        acc = __builtin_elementwise_max(acc, (f32x2){0.0f, 0.0f});

        float4 q0 = W2p[j * 3];
        float4 q1 = W2p[j * 3 + 1];
        float4 q2 = W2p[j * 3 + 2];
        o[0]  = fma2(acc, bc2(q0.x), o[0]);
        o[1]  = fma2(acc, bc2(q0.y), o[1]);
        o[2]  = fma2(acc, bc2(q0.z), o[2]);
        o[3]  = fma2(acc, bc2(q0.w), o[3]);
        o[4]  = fma2(acc, bc2(q1.x), o[4]);
        o[5]  = fma2(acc, bc2(q1.y), o[5]);
        o[6]  = fma2(acc, bc2(q1.z), o[6]);
        o[7]  = fma2(acc, bc2(q1.w), o[7]);
        o[8]  = fma2(acc, bc2(q2.x), o[8]);
        o[9]  = fma2(acc, bc2(q2.y), o[9]);
        o[10] = fma2(acc, bc2(q2.z), o[10]);
    }

    // ---- seeds for both rows (float4) ----
    float4 sd = reinterpret_cast<const float4*>(seed)[t];

    float oA[NOUT], oB[NOUT];
#pragma unroll
    for (int k = 0; k < NOUT; ++k) { oA[k] = o[k].x; oB[k] = o[k].y; }

    RowOut rA = epilogue(oA, sd.x, sd.y);
    RowOut rB = epilogue(oB, sd.z, sd.w);

    // ---- stores: z (N,2) as float4 per pair, log_p as float2 ----
    reinterpret_cast<float4*>(z_out)[t] = make_float4(rA.z0, rA.z1, rB.z0, rB.z1);
    reinterpret_cast<float2*>(logp_out)[t] = make_float2(rA.lp, rB.lp);
}

extern "C" void kernel_launch(void* const* d_in, const int* in_sizes, int n_in,
                              void* d_out, int out_size, void* d_ws, size_t ws_size,
                              hipStream_t stream)
{
    const float* cond = (const float*)d_in[0];
    const float* seed = (const float*)d_in[1];
    const float* W1   = (const float*)d_in[2];
    const float* b1   = (const float*)d_in[3];
    const float* W2   = (const float*)d_in[4];
    const float* b2   = (const float*)d_in[5];

    int N = in_sizes[1] / 2;   // randseed is (N,2)
    int Npairs = N / 2;

    float* ws = (float*)d_ws;
    float* z_out    = (float*)d_out;                   // first 2N floats
    float* logp_out = (float*)d_out + 2 * (size_t)N;   // next N floats

    pack_weights_kernel<<<1, 672, 0, stream>>>(W1, b1, W2, b2, ws);

    int block = 256;
    int grid = (Npairs + block - 1) / block;
    gmm_weighted_cond_kernel<<<grid, block, 0, stream>>>(
        cond, seed, ws, z_out, logp_out, Npairs);
}